// Round 5
// baseline (1446.815 us; speedup 1.0000x reference)
//
#include <hip/hip_runtime.h>
#include <hip/hip_bf16.h>

#define BB   2
#define NN   128
#define SS   4
#define DGG  8
#define CIN  4
#define COUT 8
#define HH   32

typedef __attribute__((ext_vector_type(4))) float          fvec4;
typedef __attribute__((ext_vector_type(4))) unsigned short usvec4;
typedef __attribute__((ext_vector_type(8))) unsigned short usvec8;
typedef __attribute__((ext_vector_type(2))) __fp16         half2v;  // matches builtin types

__device__ __forceinline__ float bf2f(unsigned short u) {
    return __uint_as_float(((unsigned int)u) << 16);
}
__device__ __forceinline__ float silu_f(float x) {
    float e = __builtin_amdgcn_exp2f(x * -1.44269504f);
    return x * __builtin_amdgcn_rcpf(1.0f + e);
}
__device__ __forceinline__ float exp_f(float x) {
    return __builtin_amdgcn_exp2f(x * 1.44269504f);
}

#if __has_builtin(__builtin_amdgcn_fdot2)
__device__ __forceinline__ float FDOT2(half2v a, half2v b, float c) {
    return __builtin_amdgcn_fdot2(a, b, c, false);
}
#else
__device__ __forceinline__ float FDOT2(half2v a, half2v b, float c) {
    return (float)a[0] * (float)b[0] + (float)a[1] * (float)b[1] + c;
}
#endif

__device__ __forceinline__ half2v upk(unsigned int u) {
    union { unsigned int u; half2v h; } x; x.u = u; return x.h;
}
__device__ __forceinline__ unsigned int pk2u(float a, float b) {
#if __has_builtin(__builtin_amdgcn_cvt_pkrtz)
    half2v h = __builtin_amdgcn_cvt_pkrtz(a, b);
#else
    half2v h; h[0] = (__fp16)a; h[1] = (__fp16)b;
#endif
    union { half2v h; unsigned int u; } x; x.h = h; return x.u;
}
__device__ __forceinline__ float bf_at(usvec4 v, int idx) {
    union { usvec4 v; unsigned long long u; } x; x.v = v;
    return bf2f((unsigned short)(x.u >> (idx * 16)));
}

// ---- dtype detection (deterministic, graph-capture safe) ----
__global__ void detect_kernel(const void* maskp, const void* cosetp, int* modes) {
    int lane = threadIdx.x;
    const unsigned short* cu = (const unsigned short*)cosetp;
    unsigned short v = cu[2 * lane];
    int e = (v >> 7) & 0xFF;
    int hit = (e >= 110 && e <= 135) ? 1 : 0;
    int hits = __popcll(__ballot(hit));
    int fmode = (hits > 32) ? 1 : 0;
    const unsigned short* mu = (const unsigned short*)maskp;
    int evenBF = 0, any3 = 0, anyByte = 0;
    for (int r = 0; r < 8; ++r) {
        int idx = lane + r * 64;
        unsigned short m = mu[idx];
        if (m == 0x3F80) { any3 = 1; if (!(idx & 1)) evenBF = 1; }
        if (m == 0x0101 || m == 0x0100) anyByte = 1;
    }
    evenBF  = (__ballot(evenBF)  != 0ull);
    any3    = (__ballot(any3)    != 0ull);
    anyByte = (__ballot(anyByte) != 0ull);
    if (lane == 0) {
        modes[0] = fmode;
        modes[1] = evenBF ? 1 : (any3 ? 3 : (anyByte ? 2 : 0));
    }
}

__device__ __forceinline__ void copy_arr(float* sm, const void* src, int off,
                                         int cnt, int fmode, int tid, int nthr) {
    if (fmode) {
        const unsigned short* s = (const unsigned short*)src;
        for (int x = tid; x < cnt; x += nthr) sm[off + x] = bf2f(s[x]);
    } else {
        const float* s = (const float*)src;
        for (int x = tid; x < cnt; x += nthr) sm[off + x] = s[x];
    }
}
// bf16 source -> packed-f16 pairs in LDS
__device__ __forceinline__ void stage_pk(unsigned int* dst, const void* src,
                                         int pairs, int tid, int nthr) {
    const unsigned short* s = (const unsigned short*)src;
    for (int x = tid; x < pairs; x += nthr)
        dst[x] = pk2u(bf2f(s[2 * x]), bf2f(s[2 * x + 1]));
}

__device__ __forceinline__ void load4(const void* p, int base, int fmode, float* dst) {
    if (fmode) {
        usvec4 v = *(const usvec4*)((const unsigned short*)p + base);
        dst[0] = bf2f(v[0]); dst[1] = bf2f(v[1]);
        dst[2] = bf2f(v[2]); dst[3] = bf2f(v[3]);
    } else {
        fvec4 v = *(const fvec4*)((const float*)p + base);
        dst[0] = v[0]; dst[1] = v[1]; dst[2] = v[2]; dst[3] = v[3];
    }
}
__device__ __forceinline__ void load8(const void* p, int base, int fmode, float* dst) {
    if (fmode) {
        usvec8 v = *(const usvec8*)((const unsigned short*)p + base);
#pragma unroll
        for (int d = 0; d < 8; ++d) dst[d] = bf2f(v[d]);
    } else {
        fvec4 a = *(const fvec4*)((const float*)p + base);
        fvec4 b = *(const fvec4*)((const float*)p + base + 4);
        dst[0] = a[0]; dst[1] = a[1]; dst[2] = a[2]; dst[3] = a[3];
        dst[4] = b[0]; dst[5] = b[1]; dst[6] = b[2]; dst[7] = b[3];
    }
}
__device__ __forceinline__ int load_mask(const void* p, int idx, int mmode) {
    if (mmode == 0) return ((const int*)p)[idx] != 0;
    if (mmode == 1) return ((const unsigned short*)p)[idx] != 0;
    if (mmode == 2) return ((const unsigned char*)p)[idx] != 0;
    return ((const unsigned int*)p)[idx] != 0;
}

// ===================== fast path: bf16 inputs, f16 dot2 =====================
// LDS layout (u32 units)
#define U_YW1  0      // 128  (4i x 32j pairs)
#define U_GW1  128    // 512  (4i x 32j x 4)
#define U_YW2  640    // 2048 (4i x 32j x 16)
#define U_GW2  2688   // 2048
#define F_YB1  4736   // 128 floats
#define F_YB2  4864
#define F_YW3  4992
#define F_YB3  5120   // 4
#define F_GB1  5124
#define F_GB2  5252
#define F_GW3  5380
#define F_GB3  5508   // 4
#define F_PART 5512   // 32 floats: [4 waves][2 s1l][4]
#define U_TOTAL 5544

// 1024 blocks: blk = bn*4 + ihalf*2 + s1h.  256 threads: tid = n2b*8+s1l*4+s2.
// Each thread: P=4 positions (n2 = n2b + p*32), 2 channels (i = ihalf*2+ii).
// Channel-split (not position-split) keeps per-CU LDS weight reads at the
// round-2 level while doubling waves/CU to 16 — round-3 showed position-split
// doubles LDS traffic and nets a loss.
__global__ __launch_bounds__(256, 4) void emha_f16(
    const void* __restrict__ g_pw, const void* __restrict__ g_coset,
    const void* __restrict__ g_mask,
    const void* yW1, const void* yb1, const void* yW2, const void* yb2,
    const void* yW3, const void* yb3,
    const void* gW1, const void* gb1, const void* gW2, const void* gb2,
    const void* gW3, const void* gb3,
    const int* modes, float* part)
{
    if (modes[0] == 0) return;   // f32 inputs -> other kernel handles
    const int mmode = modes[1];
    __shared__ unsigned int smu[U_TOTAL];
    float* smf = (float*)smu;
    const int tid = threadIdx.x;

    stage_pk(&smu[U_YW1], yW1, 128,  tid, 256);
    stage_pk(&smu[U_GW1], gW1, 512,  tid, 256);
    stage_pk(&smu[U_YW2], yW2, 2048, tid, 256);
    stage_pk(&smu[U_GW2], gW2, 2048, tid, 256);
    copy_arr(smf, yb1, F_YB1, 128, 1, tid, 256);
    copy_arr(smf, yb2, F_YB2, 128, 1, tid, 256);
    copy_arr(smf, yW3, F_YW3, 128, 1, tid, 256);
    copy_arr(smf, yb3, F_YB3, 4,   1, tid, 256);
    copy_arr(smf, gb1, F_GB1, 128, 1, tid, 256);
    copy_arr(smf, gb2, F_GB2, 128, 1, tid, 256);
    copy_arr(smf, gW3, F_GW3, 128, 1, tid, 256);
    copy_arr(smf, gb3, F_GB3, 4,   1, tid, 256);
    __syncthreads();

    const int s2  = tid & 3;
    const int s1l = (tid >> 2) & 1;
    const int n2b = tid >> 3;                 // [0,32)
    const int bn    = blockIdx.x >> 2;
    const int sub   = blockIdx.x & 3;
    const int ihalf = sub >> 1;
    const int s1h   = sub & 1;
    const int s1 = s1h * 2 + s1l;
    const int b  = bn >> 7;
    const int n1 = bn & 127;

    // query-side f values for our two channels
    float fb2[2];
    {
        usvec4 r = *(const usvec4*)((const unsigned short*)g_coset + (bn * SS + s1) * CIN);
        fb2[0] = bf_at(r, ihalf * 2 + 0);
        fb2[1] = bf_at(r, ihalf * 2 + 1);
    }

    float fa2[4][2];          // key-side f for our two channels, per p
    unsigned int gpk[4][4];   // pairwise_g packed f16, per p
    int mbits = 0;
#pragma unroll
    for (int p = 0; p < 4; ++p) {
        const int n2 = n2b + p * 32;
        usvec4 r = *(const usvec4*)((const unsigned short*)g_coset + ((b * NN + n2) * SS + s2) * CIN);
        fa2[p][0] = bf_at(r, ihalf * 2 + 0);
        fa2[p][1] = bf_at(r, ihalf * 2 + 1);
        const int pos = (((b * NN + n1) * NN + n2) * SS + s1) * SS + s2;
        usvec8 graw = *(const usvec8*)((const unsigned short*)g_pw + pos * DGG);
#pragma unroll
        for (int q = 0; q < 4; ++q)
            gpk[p][q] = pk2u(bf2f(graw[2 * q]), bf2f(graw[2 * q + 1]));
        mbits |= load_mask(g_mask, (b * NN + n2) * SS + s2, mmode) << p;
    }

    float accN[2] = {0.f, 0.f}, accD[2] = {0.f, 0.f};

#pragma unroll
    for (int ii = 0; ii < 2; ++ii) {
        const int i = ihalf * 2 + ii;
        unsigned int fabpk[4];
#pragma unroll
        for (int p = 0; p < 4; ++p) fabpk[p] = pk2u(fa2[p][ii], fb2[ii]);

        unsigned int h1pk[4][16];
        // ---- ky layer 1: h1 = silu(w0*fa + w1*fb + b) ----
        {
            const unsigned int* W1 = &smu[U_YW1 + i * 32];
            const float* B1 = &smf[F_YB1 + i * HH];
#pragma unroll
            for (int jj = 0; jj < 16; ++jj) {
                float hv[4][2];
#pragma unroll
                for (int e = 0; e < 2; ++e) {
                    half2v w = upk(W1[2 * jj + e]);
                    float c = B1[2 * jj + e];
#pragma unroll
                    for (int p = 0; p < 4; ++p)
                        hv[p][e] = silu_f(FDOT2(w, upk(fabpk[p]), c));
                }
#pragma unroll
                for (int p = 0; p < 4; ++p) h1pk[p][jj] = pk2u(hv[p][0], hv[p][1]);
            }
        }
        // ---- ky layers 2+3 fused ----
        float kyv[4];
        {
            const unsigned int* W2 = &smu[U_YW2 + i * 512];
            const float* B2 = &smf[F_YB2 + i * HH];
            const float* W3 = &smf[F_YW3 + i * HH];
            float a3[4] = {0.f, 0.f, 0.f, 0.f};
#pragma unroll 2
            for (int j = 0; j < HH; ++j) {
                const unsigned int* row = &W2[j * 16];
                float bb = B2[j];
                float d[4] = {bb, bb, bb, bb};
#pragma unroll
                for (int k2 = 0; k2 < 16; ++k2) {
                    half2v w = upk(row[k2]);
#pragma unroll
                    for (int p = 0; p < 4; ++p) d[p] = FDOT2(w, upk(h1pk[p][k2]), d[p]);
                }
                float w3 = W3[j];
#pragma unroll
                for (int p = 0; p < 4; ++p) a3[p] += w3 * silu_f(d[p]);
            }
            float b3 = smf[F_YB3 + i];
#pragma unroll
            for (int p = 0; p < 4; ++p) kyv[p] = silu_f(a3[p] + b3);
        }
        // ---- kg layer 1 ----
        {
            const unsigned int* W1 = &smu[U_GW1 + i * 128];
            const float* B1 = &smf[F_GB1 + i * HH];
#pragma unroll
            for (int jj = 0; jj < 16; ++jj) {
                float hv[4][2];
#pragma unroll
                for (int e = 0; e < 2; ++e) {
                    const unsigned int* r = &W1[(2 * jj + e) * 4];
                    float bb = B1[2 * jj + e];
#pragma unroll
                    for (int p = 0; p < 4; ++p) {
                        float t = bb;
#pragma unroll
                        for (int q = 0; q < 4; ++q)
                            t = FDOT2(upk(r[q]), upk(gpk[p][q]), t);
                        hv[p][e] = silu_f(t);
                    }
                }
#pragma unroll
                for (int p = 0; p < 4; ++p) h1pk[p][jj] = pk2u(hv[p][0], hv[p][1]);
            }
        }
        // ---- kg layers 2+3 fused ----
        float kgv[4];
        {
            const unsigned int* W2 = &smu[U_GW2 + i * 512];
            const float* B2 = &smf[F_GB2 + i * HH];
            const float* W3 = &smf[F_GW3 + i * HH];
            float a3[4] = {0.f, 0.f, 0.f, 0.f};
#pragma unroll 2
            for (int j = 0; j < HH; ++j) {
                const unsigned int* row = &W2[j * 16];
                float bb = B2[j];
                float d[4] = {bb, bb, bb, bb};
#pragma unroll
                for (int k2 = 0; k2 < 16; ++k2) {
                    half2v w = upk(row[k2]);
#pragma unroll
                    for (int p = 0; p < 4; ++p) d[p] = FDOT2(w, upk(h1pk[p][k2]), d[p]);
                }
                float w3 = W3[j];
#pragma unroll
                for (int p = 0; p < 4; ++p) a3[p] += w3 * silu_f(d[p]);
            }
            float b3 = smf[F_GB3 + i];
#pragma unroll
            for (int p = 0; p < 4; ++p) kgv[p] = silu_f(a3[p] + b3);
        }
#pragma unroll
        for (int p = 0; p < 4; ++p) {
            float e = ((mbits >> p) & 1) ? exp_f(kyv[p] + kgv[p]) : 0.f;
            accD[ii] += e;
            accN[ii] += e * fa2[p][ii];
        }
    }

    // reduce over s2 (lane bits 0,1) and n2b low bits (lane bits 3,4,5)
#pragma unroll
    for (int ii = 0; ii < 2; ++ii) {
        accN[ii] += __shfl_xor(accN[ii], 1);
        accD[ii] += __shfl_xor(accD[ii], 1);
        accN[ii] += __shfl_xor(accN[ii], 2);
        accD[ii] += __shfl_xor(accD[ii], 2);
        accN[ii] += __shfl_xor(accN[ii], 8);
        accD[ii] += __shfl_xor(accD[ii], 8);
        accN[ii] += __shfl_xor(accN[ii], 16);
        accD[ii] += __shfl_xor(accD[ii], 16);
        accN[ii] += __shfl_xor(accN[ii], 32);
        accD[ii] += __shfl_xor(accD[ii], 32);
    }
    const int lane = tid & 63;
    const int wave = tid >> 6;
    if ((lane & 59) == 0) {   // lanes 0,4: s1l = 0,1
        const int ps1l = (lane >> 2) & 1;
        float* pp = &smf[F_PART + (wave * 2 + ps1l) * 4];
        pp[0] = accN[0]; pp[1] = accD[0]; pp[2] = accN[1]; pp[3] = accD[1];
    }
    __syncthreads();
    if (tid < 8) {
        const int ps1l = tid >> 2, q = tid & 3;
        float v = 0.f;
#pragma unroll
        for (int w = 0; w < 4; ++w) v += smf[F_PART + (w * 2 + ps1l) * 4 + q];
        const int i = ihalf * 2 + (q >> 1);
        const int nd = q & 1;
        const int os1 = s1h * 2 + ps1l;
        part[(bn * 4 + os1) * 8 + i * 2 + nd] = v;
    }
}

// ===================== fallback: f32 inputs (round-2 proven path) ==========
#define O_YW1  0
#define O_YB1  256
#define O_YW2  384
#define O_YB2  4480
#define O_YW3  4608
#define O_YB3  4736
#define O_GW1  4740
#define O_GB1  5764
#define O_GW2  5892
#define O_GB2  9988
#define O_GW3  10116
#define O_GB3  10244
#define W_TOTAL 10248
#define O_PART  W_TOTAL
#define SM_TOTAL (W_TOTAL + 256)

__global__ __launch_bounds__(512, 2) void emha_f32(
    const void* __restrict__ g_pw, const void* __restrict__ g_coset,
    const void* __restrict__ g_mask,
    const void* yW1, const void* yb1, const void* yW2, const void* yb2,
    const void* yW3, const void* yb3,
    const void* gW1, const void* gb1, const void* gW2, const void* gb2,
    const void* gW3, const void* gb3,
    const int* modes, float* part)
{
    if (modes[0] != 0) return;   // bf16 inputs -> emha_f16 handles
    const int mmode = modes[1];
    __shared__ float sm[SM_TOTAL];
    const int tid = threadIdx.x;
    const int bn = blockIdx.x;
    const int b  = bn >> 7;
    const int n1 = bn & 127;

    copy_arr(sm, yW1, O_YW1, 256,  0, tid, 512);
    copy_arr(sm, yb1, O_YB1, 128,  0, tid, 512);
    copy_arr(sm, yW2, O_YW2, 4096, 0, tid, 512);
    copy_arr(sm, yb2, O_YB2, 128,  0, tid, 512);
    copy_arr(sm, yW3, O_YW3, 128,  0, tid, 512);
    copy_arr(sm, yb3, O_YB3, 4,    0, tid, 512);
    copy_arr(sm, gW1, O_GW1, 1024, 0, tid, 512);
    copy_arr(sm, gb1, O_GB1, 128,  0, tid, 512);
    copy_arr(sm, gW2, O_GW2, 4096, 0, tid, 512);
    copy_arr(sm, gb2, O_GB2, 128,  0, tid, 512);
    copy_arr(sm, gW3, O_GW3, 128,  0, tid, 512);
    copy_arr(sm, gb3, O_GB3, 4,    0, tid, 512);
    __syncthreads();

    const int s2  = tid & 3;
    const int s1  = (tid >> 2) & 3;
    const int n2b = tid >> 4;

    float fb[4];
    load4(g_coset, ((b * NN + n1) * SS + s1) * CIN, 0, fb);

    float fa[2][4], gv[2][8];
    float accN[4] = {0.f, 0.f, 0.f, 0.f};
    float accD[4] = {0.f, 0.f, 0.f, 0.f};

#pragma unroll 1
    for (int pair = 0; pair < 2; ++pair) {
        int mbits = 0;
#pragma unroll
        for (int p = 0; p < 2; ++p) {
            const int n2 = n2b + (pair * 2 + p) * 32;
            const int pos = (((b * NN + n1) * NN + n2) * SS + s1) * SS + s2;
            load8(g_pw, pos * DGG, 0, gv[p]);
            load4(g_coset, ((b * NN + n2) * SS + s2) * CIN, 0, fa[p]);
            mbits |= load_mask(g_mask, (b * NN + n2) * SS + s2, mmode) << p;
        }
#pragma unroll
        for (int i = 0; i < CIN; ++i) {
            float h1[2][HH];
            {
                const float* W1 = &sm[O_YW1 + i * 64];
                const float* B1 = &sm[O_YB1 + i * HH];
#pragma unroll
                for (int j = 0; j < HH; ++j) {
                    float w0 = W1[2 * j], w1 = W1[2 * j + 1];
                    float c = w1 * fb[i] + B1[j];
#pragma unroll
                    for (int p = 0; p < 2; ++p)
                        h1[p][j] = silu_f(w0 * fa[p][i] + c);
                }
            }
            float kyv[2];
            {
                const float* W2 = &sm[O_YW2 + i * 1024];
                const float* B2 = &sm[O_YB2 + i * HH];
                const float* W3 = &sm[O_YW3 + i * HH];
                float a3[2] = {0.f, 0.f};
#pragma unroll 2
                for (int j = 0; j < HH; ++j) {
                    float d[2] = {0.f, 0.f};
#pragma unroll
                    for (int k = 0; k < HH; ++k) {
                        float w = W2[j * HH + k];
#pragma unroll
                        for (int p = 0; p < 2; ++p) d[p] += w * h1[p][k];
                    }
                    float bb = B2[j], w3 = W3[j];
#pragma unroll
                    for (int p = 0; p < 2; ++p) a3[p] += w3 * silu_f(d[p] + bb);
                }
                float b3 = sm[O_YB3 + i];
#pragma unroll
                for (int p = 0; p < 2; ++p) kyv[p] = silu_f(a3[p] + b3);
            }
            {
                const float* W1 = &sm[O_GW1 + i * 256];
                const float* B1 = &sm[O_GB1 + i * HH];
#pragma unroll
                for (int j = 0; j < HH; ++j) {
                    float bb = B1[j];
                    float d[2] = {bb, bb};
#pragma unroll
                    for (int d8 = 0; d8 < DGG; ++d8) {
                        float w = W1[j * DGG + d8];
#pragma unroll
                        for (int p = 0; p < 2; ++p) d[p] += w * gv[p][d8];
                    }
#pragma unroll
                    for (int p = 0; p < 2; ++p) h1[p][j] = silu_f(d[p]);
                }
            }
            float kgv[2];
            {
                const float* W2 = &sm[O_GW2 + i * 1024];
                const float* B2 = &sm[O_GB2 + i * HH];
                const float* W3 = &sm[O_GW3 + i * HH];
                float a3[2] = {0.f, 0.f};
#pragma unroll 2
                for (int j = 0; j < HH; ++j) {
                    float d[2] = {0.f, 0.f};
#pragma unroll
                    for (int k = 0; k < HH; ++k) {
                        float w = W2[j * HH + k];
#pragma unroll
                        for (int p = 0; p < 2; ++p) d[p] += w * h1[p][k];
                    }
                    float bb = B2[j], w3 = W3[j];
#pragma unroll
                    for (int p = 0; p < 2; ++p) a3[p] += w3 * silu_f(d[p] + bb);
                }
                float b3 = sm[O_GB3 + i];
#pragma unroll
                for (int p = 0; p < 2; ++p) kgv[p] = silu_f(a3[p] + b3);
            }
#pragma unroll
            for (int p = 0; p < 2; ++p) {
                float e = ((mbits >> p) & 1) ? exp_f(kyv[p] + kgv[p]) : 0.f;
                accD[i] += e;
                accN[i] += e * fa[p][i];
            }
        }
    }

#pragma unroll
    for (int i = 0; i < CIN; ++i) {
        accN[i] += __shfl_xor(accN[i], 1);
        accD[i] += __shfl_xor(accD[i], 1);
        accN[i] += __shfl_xor(accN[i], 2);
        accD[i] += __shfl_xor(accD[i], 2);
        accN[i] += __shfl_xor(accN[i], 16);
        accD[i] += __shfl_xor(accD[i], 16);
        accN[i] += __shfl_xor(accN[i], 32);
        accD[i] += __shfl_xor(accD[i], 32);
    }
    const int lane = tid & 63;
    const int wave = tid >> 6;
    if ((lane & 51) == 0) {
        const int ps1 = (lane >> 2) & 3;
        float* p = &sm[O_PART + (wave * 4 + ps1) * 8];
#pragma unroll
        for (int i = 0; i < CIN; ++i) {
            p[i * 2]     = accN[i];
            p[i * 2 + 1] = accD[i];
        }
    }
    __syncthreads();
    if (tid < 32) {
        const int ps1 = tid >> 3, j = tid & 7;
        float v = 0.f;
#pragma unroll
        for (int w = 0; w < 8; ++w) v += sm[O_PART + (w * 4 + ps1) * 8 + j];
        part[(bn * 4 + ps1) * 8 + j] = v;
    }
}

// ===================== finalize ============================================
__global__ void finalize_kernel(const void* __restrict__ g_coset,
                                const void* __restrict__ g_mask,
                                const void* wout, const float* part,
                                const int* modes, void* outp) {
    const int t = blockIdx.x * 256 + threadIdx.x;  // [0,1024)
    const int fmode = modes[0], mmode = modes[1];
    const int bn = t >> 2;
    const int s1 = t & 3;

    float fb[4];
    load4(g_coset, (bn * SS + s1) * CIN, fmode, fb);
    const int m1 = load_mask(g_mask, bn * SS + s1, mmode);

    float cf[4];
#pragma unroll
    for (int i = 0; i < CIN; ++i) {
        float num = part[(bn * 4 + s1) * 8 + i * 2];
        float den = part[(bn * 4 + s1) * 8 + i * 2 + 1];
        cf[i] = m1 ? (fb[i] + num * __builtin_amdgcn_rcpf(den)) : 0.f;
    }
#pragma unroll
    for (int o = 0; o < COUT; ++o) {
        float wv[4];
        load4(wout, o * CIN, fmode, wv);
        float v = cf[0] * wv[0] + cf[1] * wv[1] + cf[2] * wv[2] + cf[3] * wv[3];
        const int oidx = (bn * SS + s1) * COUT + o;
        if (fmode) ((__hip_bfloat16*)outp)[oidx] = __float2bfloat16(v);
        else       ((float*)outp)[oidx] = v;
    }
}

extern "C" void kernel_launch(void* const* d_in, const int* in_sizes, int n_in,
                              void* d_out, int out_size, void* d_ws, size_t ws_size,
                              hipStream_t stream) {
    int*   modes = (int*)d_ws;                   // 2 ints
    float* part  = (float*)((char*)d_ws + 256);  // 256*4*8 floats
    detect_kernel<<<1, 64, 0, stream>>>(d_in[2], d_in[1], modes);
    emha_f32<<<BB * NN, 512, 0, stream>>>(
        d_in[0], d_in[1], d_in[2],
        d_in[3], d_in[4], d_in[5], d_in[6], d_in[7], d_in[8],
        d_in[9], d_in[10], d_in[11], d_in[12], d_in[13], d_in[14],
        modes, part);
    emha_f16<<<4 * BB * NN, 256, 0, stream>>>(
        d_in[0], d_in[1], d_in[2],
        d_in[3], d_in[4], d_in[5], d_in[6], d_in[7], d_in[8],
        d_in[9], d_in[10], d_in[11], d_in[12], d_in[13], d_in[14],
        modes, part);
    finalize_kernel<<<4, 256, 0, stream>>>(d_in[1], d_in[2], d_in[15], part,
                                           modes, d_out);
}

// Round 6
// 236.746 us; speedup vs baseline: 6.1112x; 6.1112x over previous
//
#include <hip/hip_runtime.h>
#include <hip/hip_bf16.h>

#define BB   2
#define NN   128
#define SS   4
#define DGG  8
#define CIN  4
#define COUT 8
#define HH   32

typedef __attribute__((ext_vector_type(4))) float          fvec4;
typedef __attribute__((ext_vector_type(4))) unsigned short usvec4;
typedef __attribute__((ext_vector_type(8))) unsigned short usvec8;
typedef __attribute__((ext_vector_type(2))) __fp16         half2v;

__device__ __forceinline__ float bf2f(unsigned short u) {
    return __uint_as_float(((unsigned int)u) << 16);
}
__device__ __forceinline__ float silu_f(float x) {
    float e = __builtin_amdgcn_exp2f(x * -1.44269504f);
    return x * __builtin_amdgcn_rcpf(1.0f + e);
}
__device__ __forceinline__ float exp_f(float x) {
    return __builtin_amdgcn_exp2f(x * 1.44269504f);
}

#if __has_builtin(__builtin_amdgcn_fdot2)
__device__ __forceinline__ float FDOT2(half2v a, half2v b, float c) {
    return __builtin_amdgcn_fdot2(a, b, c, false);
}
#else
__device__ __forceinline__ float FDOT2(half2v a, half2v b, float c) {
    return (float)a[0] * (float)b[0] + (float)a[1] * (float)b[1] + c;
}
#endif

__device__ __forceinline__ half2v upk(unsigned int u) {
    union { unsigned int u; half2v h; } x; x.u = u; return x.h;
}
__device__ __forceinline__ unsigned int pk2u(float a, float b) {
#if __has_builtin(__builtin_amdgcn_cvt_pkrtz)
    half2v h = __builtin_amdgcn_cvt_pkrtz(a, b);
#else
    half2v h; h[0] = (__fp16)a; h[1] = (__fp16)b;
#endif
    union { half2v h; unsigned int u; } x; x.h = h; return x.u;
}

// ---- dtype detection (deterministic, graph-capture safe) ----
// modes[0]: 0 = float tensors are f32 (confirmed live in round 5), 1 = bf16
// modes[1]: mask dtype: 0=i32, 1=bf16, 2=u8/bool, 3=f32
__global__ void detect_kernel(const void* maskp, const void* cosetp, int* modes) {
    int lane = threadIdx.x;
    const unsigned short* cu = (const unsigned short*)cosetp;
    unsigned short v = cu[2 * lane];
    int e = (v >> 7) & 0xFF;
    int hit = (e >= 110 && e <= 135) ? 1 : 0;
    int hits = __popcll(__ballot(hit));
    int fmode = (hits > 32) ? 1 : 0;
    const unsigned short* mu = (const unsigned short*)maskp;
    int evenBF = 0, any3 = 0, anyByte = 0;
    for (int r = 0; r < 8; ++r) {
        int idx = lane + r * 64;
        unsigned short m = mu[idx];
        if (m == 0x3F80) { any3 = 1; if (!(idx & 1)) evenBF = 1; }
        if (m == 0x0101 || m == 0x0100) anyByte = 1;
    }
    evenBF  = (__ballot(evenBF)  != 0ull);
    any3    = (__ballot(any3)    != 0ull);
    anyByte = (__ballot(anyByte) != 0ull);
    if (lane == 0) {
        modes[0] = fmode;
        modes[1] = evenBF ? 1 : (any3 ? 3 : (anyByte ? 2 : 0));
    }
}

// stage weights (f32 or bf16 source) as packed-f16 pairs in LDS
__device__ __forceinline__ void stage_pk(unsigned int* dst, const void* src,
                                         int pairs, int fmode, int tid, int nthr) {
    if (fmode) {
        const unsigned short* s = (const unsigned short*)src;
        for (int x = tid; x < pairs; x += nthr)
            dst[x] = pk2u(bf2f(s[2 * x]), bf2f(s[2 * x + 1]));
    } else {
        const float* s = (const float*)src;
        for (int x = tid; x < pairs; x += nthr)
            dst[x] = pk2u(s[2 * x], s[2 * x + 1]);
    }
}
__device__ __forceinline__ void copy_arr(float* sm, const void* src, int off,
                                         int cnt, int fmode, int tid, int nthr) {
    if (fmode) {
        const unsigned short* s = (const unsigned short*)src;
        for (int x = tid; x < cnt; x += nthr) sm[off + x] = bf2f(s[x]);
    } else {
        const float* s = (const float*)src;
        for (int x = tid; x < cnt; x += nthr) sm[off + x] = s[x];
    }
}
__device__ __forceinline__ void load4(const void* p, int base, int fmode, float* dst) {
    if (fmode) {
        usvec4 v = *(const usvec4*)((const unsigned short*)p + base);
        dst[0] = bf2f(v[0]); dst[1] = bf2f(v[1]);
        dst[2] = bf2f(v[2]); dst[3] = bf2f(v[3]);
    } else {
        fvec4 v = *(const fvec4*)((const float*)p + base);
        dst[0] = v[0]; dst[1] = v[1]; dst[2] = v[2]; dst[3] = v[3];
    }
}
__device__ __forceinline__ void load8(const void* p, int base, int fmode, float* dst) {
    if (fmode) {
        usvec8 v = *(const usvec8*)((const unsigned short*)p + base);
#pragma unroll
        for (int d = 0; d < 8; ++d) dst[d] = bf2f(v[d]);
    } else {
        fvec4 a = *(const fvec4*)((const float*)p + base);
        fvec4 b = *(const fvec4*)((const float*)p + base + 4);
        dst[0] = a[0]; dst[1] = a[1]; dst[2] = a[2]; dst[3] = a[3];
        dst[4] = b[0]; dst[5] = b[1]; dst[6] = b[2]; dst[7] = b[3];
    }
}
__device__ __forceinline__ int load_mask(const void* p, int idx, int mmode) {
    if (mmode == 0) return ((const int*)p)[idx] != 0;
    if (mmode == 1) return ((const unsigned short*)p)[idx] != 0;
    if (mmode == 2) return ((const unsigned char*)p)[idx] != 0;
    return ((const unsigned int*)p)[idx] != 0;
}

// LDS layout (u32 units)
#define U_YW1  0      // 128  pairs (4i x 32j x {w_fa,w_fb})
#define U_GW1  128    // 512  pairs (4i x 32j x 4)
#define U_YW2  640    // 2048 pairs (4i x 32j x 16)
#define U_GW2  2688   // 2048
#define F_YB1  4736   // 128 floats
#define F_YB2  4864
#define F_YW3  4992
#define F_YB3  5120   // 4
#define F_GB1  5124
#define F_GB2  5252
#define F_GW3  5380
#define F_GB3  5508   // 4
#define F_PART 5512   // 32 floats: [4 waves][2 s1l][4]
#define U_TOTAL 5544  // 22176 B -> 4 blocks/CU fits in 160 KiB

// 1024 blocks: blk = bn*4 + ihalf*2 + s1h.  256 threads: tid = n2b*8+s1l*4+s2.
// Each thread: P=4 positions (n2 = n2b + p*32, fully unrolled — NO runtime
// position loop: round-5's unroll-1 outer loop re-triggered scratch spill),
// 2 channels (i = ihalf*2+ii).  Channel-split keeps per-CU LDS weight-read
// traffic at the round-2 level while quadrupling resident waves/CU; f16
// packing halves LDS bytes and doubles MAC rate via v_dot2_f32_f16.
__global__ __launch_bounds__(256, 3) void emha_main(
    const void* __restrict__ g_pw, const void* __restrict__ g_coset,
    const void* __restrict__ g_mask,
    const void* yW1, const void* yb1, const void* yW2, const void* yb2,
    const void* yW3, const void* yb3,
    const void* gW1, const void* gb1, const void* gW2, const void* gb2,
    const void* gW3, const void* gb3,
    const int* modes, float* part)
{
    const int fmode = modes[0];
    const int mmode = modes[1];
    __shared__ unsigned int smu[U_TOTAL];
    float* smf = (float*)smu;
    const int tid = threadIdx.x;

    stage_pk(&smu[U_YW1], yW1, 128,  fmode, tid, 256);
    stage_pk(&smu[U_GW1], gW1, 512,  fmode, tid, 256);
    stage_pk(&smu[U_YW2], yW2, 2048, fmode, tid, 256);
    stage_pk(&smu[U_GW2], gW2, 2048, fmode, tid, 256);
    copy_arr(smf, yb1, F_YB1, 128, fmode, tid, 256);
    copy_arr(smf, yb2, F_YB2, 128, fmode, tid, 256);
    copy_arr(smf, yW3, F_YW3, 128, fmode, tid, 256);
    copy_arr(smf, yb3, F_YB3, 4,   fmode, tid, 256);
    copy_arr(smf, gb1, F_GB1, 128, fmode, tid, 256);
    copy_arr(smf, gb2, F_GB2, 128, fmode, tid, 256);
    copy_arr(smf, gW3, F_GW3, 128, fmode, tid, 256);
    copy_arr(smf, gb3, F_GB3, 4,   fmode, tid, 256);
    __syncthreads();

    const int s2  = tid & 3;
    const int s1l = (tid >> 2) & 1;
    const int n2b = tid >> 3;                 // [0,32)
    const int bn    = blockIdx.x >> 2;
    const int sub   = blockIdx.x & 3;
    const int ihalf = sub >> 1;
    const int s1h   = sub & 1;
    const int s1 = s1h * 2 + s1l;
    const int b  = bn >> 7;
    const int n1 = bn & 127;

    // query-side f for our two channels
    float fb2[2];
    {
        float r[4];
        load4(g_coset, (bn * SS + s1) * CIN, fmode, r);
        fb2[0] = r[ihalf * 2 + 0];
        fb2[1] = r[ihalf * 2 + 1];
    }

    float fa2[4][2];          // key-side f, per p
    unsigned int gpk[4][4];   // pairwise_g packed f16, per p
    int mbits = 0;
#pragma unroll
    for (int p = 0; p < 4; ++p) {
        const int n2 = n2b + p * 32;
        float r[4];
        load4(g_coset, ((b * NN + n2) * SS + s2) * CIN, fmode, r);
        fa2[p][0] = r[ihalf * 2 + 0];
        fa2[p][1] = r[ihalf * 2 + 1];
        const int pos = (((b * NN + n1) * NN + n2) * SS + s1) * SS + s2;
        float g8[8];
        load8(g_pw, pos * DGG, fmode, g8);
#pragma unroll
        for (int q = 0; q < 4; ++q)
            gpk[p][q] = pk2u(g8[2 * q], g8[2 * q + 1]);
        mbits |= load_mask(g_mask, (b * NN + n2) * SS + s2, mmode) << p;
    }

    float accN[2] = {0.f, 0.f}, accD[2] = {0.f, 0.f};

#pragma unroll
    for (int ii = 0; ii < 2; ++ii) {
        const int i = ihalf * 2 + ii;
        unsigned int fabpk[4];
#pragma unroll
        for (int p = 0; p < 4; ++p) fabpk[p] = pk2u(fa2[p][ii], fb2[ii]);

        unsigned int h1pk[4][16];
        // ---- ky layer 1: h1 = silu(w_fa*fa + w_fb*fb + b) ----
        {
            const unsigned int* W1 = &smu[U_YW1 + i * 32];
            const float* B1 = &smf[F_YB1 + i * HH];
#pragma unroll
            for (int jj = 0; jj < 16; ++jj) {
                float hv[4][2];
#pragma unroll
                for (int e = 0; e < 2; ++e) {
                    half2v w = upk(W1[2 * jj + e]);
                    float c = B1[2 * jj + e];
#pragma unroll
                    for (int p = 0; p < 4; ++p)
                        hv[p][e] = silu_f(FDOT2(w, upk(fabpk[p]), c));
                }
#pragma unroll
                for (int p = 0; p < 4; ++p) h1pk[p][jj] = pk2u(hv[p][0], hv[p][1]);
            }
        }
        // ---- ky layers 2+3 fused (h2 never materializes) ----
        float kyv[4];
        {
            const unsigned int* W2 = &smu[U_YW2 + i * 512];
            const float* B2 = &smf[F_YB2 + i * HH];
            const float* W3 = &smf[F_YW3 + i * HH];
            float a3[4] = {0.f, 0.f, 0.f, 0.f};
#pragma unroll 2
            for (int j = 0; j < HH; ++j) {
                const unsigned int* row = &W2[j * 16];
                float bb = B2[j];
                float d[4] = {bb, bb, bb, bb};
#pragma unroll
                for (int k2 = 0; k2 < 16; ++k2) {
                    half2v w = upk(row[k2]);
#pragma unroll
                    for (int p = 0; p < 4; ++p) d[p] = FDOT2(w, upk(h1pk[p][k2]), d[p]);
                }
                float w3 = W3[j];
#pragma unroll
                for (int p = 0; p < 4; ++p) a3[p] += w3 * silu_f(d[p]);
            }
            float b3 = smf[F_YB3 + i];
#pragma unroll
            for (int p = 0; p < 4; ++p) kyv[p] = silu_f(a3[p] + b3);
        }
        // ---- kg layer 1 ----
        {
            const unsigned int* W1 = &smu[U_GW1 + i * 128];
            const float* B1 = &smf[F_GB1 + i * HH];
#pragma unroll
            for (int jj = 0; jj < 16; ++jj) {
                float hv[4][2];
#pragma unroll
                for (int e = 0; e < 2; ++e) {
                    const unsigned int* r = &W1[(2 * jj + e) * 4];
                    float bb = B1[2 * jj + e];
#pragma unroll
                    for (int p = 0; p < 4; ++p) {
                        float t = bb;
#pragma unroll
                        for (int q = 0; q < 4; ++q)
                            t = FDOT2(upk(r[q]), upk(gpk[p][q]), t);
                        hv[p][e] = silu_f(t);
                    }
                }
#pragma unroll
                for (int p = 0; p < 4; ++p) h1pk[p][jj] = pk2u(hv[p][0], hv[p][1]);
            }
        }
        // ---- kg layers 2+3 fused ----
        float kgv[4];
        {
            const unsigned int* W2 = &smu[U_GW2 + i * 512];
            const float* B2 = &smf[F_GB2 + i * HH];
            const float* W3 = &smf[F_GW3 + i * HH];
            float a3[4] = {0.f, 0.f, 0.f, 0.f};
#pragma unroll 2
            for (int j = 0; j < HH; ++j) {
                const unsigned int* row = &W2[j * 16];
                float bb = B2[j];
                float d[4] = {bb, bb, bb, bb};
#pragma unroll
                for (int k2 = 0; k2 < 16; ++k2) {
                    half2v w = upk(row[k2]);
#pragma unroll
                    for (int p = 0; p < 4; ++p) d[p] = FDOT2(w, upk(h1pk[p][k2]), d[p]);
                }
                float w3 = W3[j];
#pragma unroll
                for (int p = 0; p < 4; ++p) a3[p] += w3 * silu_f(d[p]);
            }
            float b3 = smf[F_GB3 + i];
#pragma unroll
            for (int p = 0; p < 4; ++p) kgv[p] = silu_f(a3[p] + b3);
        }
        // ---- masked exp, accumulate ----
#pragma unroll
        for (int p = 0; p < 4; ++p) {
            float e = ((mbits >> p) & 1) ? exp_f(kyv[p] + kgv[p]) : 0.f;
            accD[ii] += e;
            accN[ii] += e * fa2[p][ii];
        }
    }

    // reduce over lane bits {0,1}=s2 and {3,4,5}=n2b-within-wave
#pragma unroll
    for (int ii = 0; ii < 2; ++ii) {
        accN[ii] += __shfl_xor(accN[ii], 1);
        accD[ii] += __shfl_xor(accD[ii], 1);
        accN[ii] += __shfl_xor(accN[ii], 2);
        accD[ii] += __shfl_xor(accD[ii], 2);
        accN[ii] += __shfl_xor(accN[ii], 8);
        accD[ii] += __shfl_xor(accD[ii], 8);
        accN[ii] += __shfl_xor(accN[ii], 16);
        accD[ii] += __shfl_xor(accD[ii], 16);
        accN[ii] += __shfl_xor(accN[ii], 32);
        accD[ii] += __shfl_xor(accD[ii], 32);
    }
    const int lane = tid & 63;
    const int wave = tid >> 6;
    if ((lane & 59) == 0) {   // lanes 0,4: s1l = 0,1
        const int ps1l = (lane >> 2) & 1;
        float* pp = &smf[F_PART + (wave * 2 + ps1l) * 4];
        pp[0] = accN[0]; pp[1] = accD[0]; pp[2] = accN[1]; pp[3] = accD[1];
    }
    __syncthreads();
    if (tid < 8) {
        const int ps1l = tid >> 2, q = tid & 3;
        float v = 0.f;
#pragma unroll
        for (int w = 0; w < 4; ++w) v += smf[F_PART + (w * 2 + ps1l) * 4 + q];
        const int i = ihalf * 2 + (q >> 1);
        const int nd = q & 1;
        const int os1 = s1h * 2 + ps1l;
        part[(bn * 4 + os1) * 8 + i * 2 + nd] = v;
    }
}

// ===================== finalize ============================================
__global__ void finalize_kernel(const void* __restrict__ g_coset,
                                const void* __restrict__ g_mask,
                                const void* wout, const float* part,
                                const int* modes, void* outp) {
    const int t = blockIdx.x * 256 + threadIdx.x;  // [0,1024)
    const int fmode = modes[0], mmode = modes[1];
    const int bn = t >> 2;
    const int s1 = t & 3;

    float fb[4];
    load4(g_coset, (bn * SS + s1) * CIN, fmode, fb);
    const int m1 = load_mask(g_mask, bn * SS + s1, mmode);

    float cf[4];
#pragma unroll
    for (int i = 0; i < CIN; ++i) {
        float num = part[(bn * 4 + s1) * 8 + i * 2];
        float den = part[(bn * 4 + s1) * 8 + i * 2 + 1];
        cf[i] = m1 ? (fb[i] + num / den) : 0.f;
    }
#pragma unroll
    for (int o = 0; o < COUT; ++o) {
        float wv[4];
        load4(wout, o * CIN, fmode, wv);
        float v = cf[0] * wv[0] + cf[1] * wv[1] + cf[2] * wv[2] + cf[3] * wv[3];
        const int oidx = (bn * SS + s1) * COUT + o;
        if (fmode) ((__hip_bfloat16*)outp)[oidx] = __float2bfloat16(v);
        else       ((float*)outp)[oidx] = v;
    }
}

extern "C" void kernel_launch(void* const* d_in, const int* in_sizes, int n_in,
                              void* d_out, int out_size, void* d_ws, size_t ws_size,
                              hipStream_t stream) {
    int*   modes = (int*)d_ws;                   // 2 ints
    float* part  = (float*)((char*)d_ws + 256);  // 256*4*8 floats
    detect_kernel<<<1, 64, 0, stream>>>(d_in[2], d_in[1], modes);
    emha_main<<<4 * BB * NN, 256, 0, stream>>>(
        d_in[0], d_in[1], d_in[2],
        d_in[3], d_in[4], d_in[5], d_in[6], d_in[7], d_in[8],
        d_in[9], d_in[10], d_in[11], d_in[12], d_in[13], d_in[14],
        modes, part);
    finalize_kernel<<<4, 256, 0, stream>>>(d_in[1], d_in[2], d_in[15], part,
                                           modes, d_out);
}